// Round 3
// baseline (47.350 us; speedup 1.0000x reference)
//
#include <hip/hip_runtime.h>
#include <math.h>

#define NN 1024
#define BTH 256
#define TOPK 3
#define NT 16              // NN/64 tile-chunks per row
#define NTILES 136         // NT*(NT+1)/2 upper-triangle 64x64 tiles
#define GRIDX (NTILES / 4) // 34 blocks per batch, 4 waves = 4 tiles each

// ---------------------------------------------------------------------------
// One fused kernel. grid = (34, B). Per block:
//   1. load full pred/rel row (registers + LDS)
//   2. inline top-3 (tie-break: lower index) -> mult on the fly
//   3. 4 waves x 1 upper-triangle 64x64 tile, symmetry x2, in-loop valid count
//   4. last-finished block reduces all partials -> out[0]
// ---------------------------------------------------------------------------
__global__ void __launch_bounds__(BTH)
fused_kernel(const float* __restrict__ pred,
             const float* __restrict__ rel,
             float* __restrict__ psum,
             float* __restrict__ pcnt,
             unsigned int* __restrict__ ctr,
             float* __restrict__ out, int B) {
    const int b = blockIdx.y;
    const int t = threadIdx.x;
    const int w = t >> 6;
    const int l = t & 63;
    const int L = blockIdx.x * 4 + w;   // tile id 0..135

    __shared__ float s_p[NN];
    __shared__ float s_r[NN];
    __shared__ float s_m[NN];
    __shared__ float s_rv[TOPK][4];
    __shared__ int   s_ri[TOPK][4];
    __shared__ int   s_flag;
    __shared__ float s_l[32];

    const size_t base = (size_t)b * NN;
    const float4 p4 = ((const float4*)(pred + base))[t];
    const float4 r4 = ((const float4*)(rel  + base))[t];
    ((float4*)s_p)[t] = p4;
    ((float4*)s_r)[t] = r4;

    // ---- inline top-3 over the row (every thread ends with the winners) ----
    int w1 = -1, w2 = -1, w3 = -1;
    const int n0 = t * 4;
    for (int k = 0; k < TOPK; ++k) {
        float bv = -INFINITY;
        int   bi = NN;
        {   // scan own 4 elements (ascending n + strict '>' keeps lowest idx)
            float v0 = p4.x, v1 = p4.y, v2 = p4.z, v3 = p4.w;
            if (n0 + 0 != w1 && n0 + 0 != w2 && v0 > bv) { bv = v0; bi = n0 + 0; }
            if (n0 + 1 != w1 && n0 + 1 != w2 && v1 > bv) { bv = v1; bi = n0 + 1; }
            if (n0 + 2 != w1 && n0 + 2 != w2 && v2 > bv) { bv = v2; bi = n0 + 2; }
            if (n0 + 3 != w1 && n0 + 3 != w2 && v3 > bv) { bv = v3; bi = n0 + 3; }
        }
        for (int off = 32; off > 0; off >>= 1) {
            float ov = __shfl_xor(bv, off);
            int   oi = __shfl_xor(bi, off);
            if (ov > bv || (ov == bv && oi < bi)) { bv = ov; bi = oi; }
        }
        if (l == 0) { s_rv[k][w] = bv; s_ri[k][w] = bi; }
        __syncthreads();
        bv = s_rv[k][0]; bi = s_ri[k][0];
        for (int q = 1; q < 4; ++q) {
            float ov = s_rv[k][q]; int oi = s_ri[k][q];
            if (ov > bv || (ov == bv && oi < bi)) { bv = ov; bi = oi; }
        }
        if (k == 0) w1 = bi; else if (k == 1) w2 = bi; else w3 = bi;
    }

    // mult row -> LDS
    {
        float4 m4;
        m4.x = (n0 + 0 == w1 || n0 + 0 == w2 || n0 + 0 == w3) ? 2.0f : 1.0f;
        m4.y = (n0 + 1 == w1 || n0 + 1 == w2 || n0 + 1 == w3) ? 2.0f : 1.0f;
        m4.z = (n0 + 2 == w1 || n0 + 2 == w2 || n0 + 2 == w3) ? 2.0f : 1.0f;
        m4.w = (n0 + 3 == w1 || n0 + 3 == w2 || n0 + 3 == w3) ? 2.0f : 1.0f;
        ((float4*)s_m)[t] = m4;
    }
    __syncthreads();

    // ---- tile: decode L -> (ti, tj), tj >= ti ----
    int rem = L, ti = 0;
    while (rem >= NT - ti) { rem -= NT - ti; ++ti; }
    const int tj = ti + rem;
    const int i0 = ti * 64, j0 = tj * 64;
    const bool diag = (ti == tj);

    const float jp = s_p[j0 + l];
    const float jr = s_r[j0 + l];
    const float jm = s_m[j0 + l];

    float acc = 0.0f, cnt = 0.0f;
#pragma unroll 8
    for (int ii = 0; ii < 64; ++ii) {
        const float pi = s_p[i0 + ii];
        const float ri = s_r[i0 + ii];
        const float mi = s_m[i0 + ii];
        const float x  = pi - jp;
        const float e  = __expf(-fabsf(x));
        const float sp = fmaxf(x, 0.0f) + __logf(1.0f + e);
        const float s2 = (ri > jr) ? (sp - x) : sp;        // sp - t*x
        const bool keep = (ri != jr) && (!diag || l > ii);
        acc = fmaf(keep ? mi * jm : 0.0f, s2, acc);
        cnt += keep ? 1.0f : 0.0f;
    }

    for (int off = 32; off > 0; off >>= 1) {
        acc += __shfl_down(acc, off);
        cnt += __shfl_down(cnt, off);
    }
    if (l == 0) {
        psum[(size_t)b * NTILES + L] = acc * 2.0f;   // both pair orders
        pcnt[(size_t)b * NTILES + L] = cnt * 2.0f;
    }

    // ---- last-block finalize ----
    __syncthreads();
    if (t == 0) {
        __threadfence();                               // release partials
        unsigned int old = atomicAdd(ctr, 1u);
        s_flag = (old == (unsigned int)(gridDim.x * gridDim.y) - 1u) ? 1 : 0;
    }
    __syncthreads();
    if (s_flag) {
        __threadfence();                               // acquire partials
        const int bb = t >> 3;
        const int k  = t & 7;
        float s = 0.0f, c = 0.0f;
        for (int e = k; e < NTILES; e += 8) {
            s += psum[(size_t)bb * NTILES + e];
            c += pcnt[(size_t)bb * NTILES + e];
        }
        s += __shfl_xor(s, 1); c += __shfl_xor(c, 1);
        s += __shfl_xor(s, 2); c += __shfl_xor(c, 2);
        s += __shfl_xor(s, 4); c += __shfl_xor(c, 4);
        if (k == 0) s_l[bb] = s / (c + 1e-8f);
        __syncthreads();
        if (t == 0) {
            float m = 0.0f;
            for (int i = 0; i < B; ++i) m += s_l[i];
            out[0] = m / (float)B;
        }
    }
}

extern "C" void kernel_launch(void* const* d_in, const int* in_sizes, int n_in,
                              void* d_out, int out_size, void* d_ws, size_t ws_size,
                              hipStream_t stream) {
    const float* pred = (const float*)d_in[0];
    const float* rel  = (const float*)d_in[1];
    float* out = (float*)d_out;

    const int B = in_sizes[0] / NN;  // 32

    // ws layout: [ctr + pad : 64B] | psum[B*NTILES] | pcnt[B*NTILES]
    unsigned int* ctr = (unsigned int*)d_ws;
    float* psum = (float*)((char*)d_ws + 64);
    float* pcnt = psum + (size_t)B * NTILES;

    hipMemsetAsync(d_ws, 0, 64, stream);  // reset completion counter per launch
    fused_kernel<<<dim3(GRIDX, B), BTH, 0, stream>>>(pred, rel, psum, pcnt, ctr, out, B);
}

// Round 4
// 24.772 us; speedup vs baseline: 1.9114x; 1.9114x over previous
//
#include <hip/hip_runtime.h>
#include <math.h>

#define NN 1024
#define BTH 256
#define NT 16              // NN/64 tile-chunks per row
#define NTILES 136         // NT*(NT+1)/2 upper-triangle 64x64 tiles
#define TBLK 34            // tile blocks per batch (4 waves = 4 tiles each)

// f(i,j) = softplus(x) - t*x  (t = [ri>rj], valid = [ri!=rj])
//        = softplus(y) with y = (t ? -x : x);   symmetric: f(i,j)=f(j,i)
__device__ __forceinline__ float pair_f(float pi, float ri, float pj, float rj) {
    const float x = pi - pj;
    const float y = (ri > rj) ? -x : x;
    const float e = __expf(-fabsf(y));
    const float f = fmaxf(y, 0.0f) + __logf(1.0f + e);
    return (ri != rj) ? f : 0.0f;
}

// ---------------------------------------------------------------------------
// Role-split kernel. blocks [0, TBLK*B): unweighted pairwise tiles.
// blocks [TBLK*B, TBLK*B+B): per-batch top-3 -> correction + valid count.
// ---------------------------------------------------------------------------
__global__ void __launch_bounds__(BTH)
main_kernel(const float* __restrict__ pred, const float* __restrict__ rel,
            float* __restrict__ psum, float* __restrict__ corr,
            float* __restrict__ cntv, int B) {
    const int t = threadIdx.x;
    const int blk = blockIdx.x;
    const int ntb = TBLK * B;

    if (blk < ntb) {
        // ------------------ tile path: one wave per 64x64 tile ------------------
        __shared__ float2 s_seg[4][64];
        const int w = t >> 6, l = t & 63;
        const int b = blk / TBLK;
        const int L = (blk % TBLK) * 4 + w;     // 0..135
        int rem = L, ti = 0;
        while (rem >= NT - ti) { rem -= NT - ti; ++ti; }
        const int tj = ti + rem;
        const size_t base = (size_t)b * NN;
        const int i0 = ti * 64, j0 = tj * 64;

        const float jp = pred[base + j0 + l];
        const float jr = rel [base + j0 + l];
        s_seg[w][l] = make_float2(pred[base + i0 + l], rel[base + i0 + l]);
        // per-wave private LDS segment: no block barrier needed (lgkmcnt orders)

        float acc = 0.0f;
        if (ti != tj) {
#pragma unroll 16
            for (int ii = 0; ii < 64; ++ii) {
                const float2 v = s_seg[w][ii];
                acc += pair_f(v.x, v.y, jp, jr);
            }
        } else {
#pragma unroll 16
            for (int ii = 0; ii < 64; ++ii) {
                const float2 v = s_seg[w][ii];
                const float f = pair_f(v.x, v.y, jp, jr);
                acc += (l > ii) ? f : 0.0f;     // strict upper triangle
            }
        }
        for (int off = 32; off > 0; off >>= 1) acc += __shfl_down(acc, off);
        if (l == 0) psum[(size_t)b * NTILES + L] = acc * 2.0f;  // both orders
    } else {
        // ------------------ top-k path: one block per batch ------------------
        const int b = blk - ntb;
        __shared__ float s_p[NN];
        __shared__ float s_r[NN];
        __shared__ float s_wk[NN];
        __shared__ float s_val[BTH];
        __shared__ int   s_idx[BTH];
        __shared__ int   s_win[3];
        __shared__ int   s_hist[5];
        __shared__ float s_red[4];
        const size_t base = (size_t)b * NN;

        if (t < 5) s_hist[t] = 0;
        __syncthreads();
        const float4 p4 = ((const float4*)(pred + base))[t];
        const float4 r4 = ((const float4*)(rel  + base))[t];
        ((float4*)s_p)[t]  = p4;
        ((float4*)s_r)[t]  = r4;
        ((float4*)s_wk)[t] = p4;
        atomicAdd(&s_hist[(int)r4.x], 1);
        atomicAdd(&s_hist[(int)r4.y], 1);
        atomicAdd(&s_hist[(int)r4.z], 1);
        atomicAdd(&s_hist[(int)r4.w], 1);
        __syncthreads();

        for (int k = 0; k < 3; ++k) {   // top-3, lower index wins ties
            float bv = -INFINITY; int bi = NN;
            for (int n = t; n < NN; n += BTH) {
                const float v = s_wk[n];
                if (v > bv) { bv = v; bi = n; }   // ascending n + strict '>'
            }
            s_val[t] = bv; s_idx[t] = bi;
            __syncthreads();
            for (int off = BTH / 2; off > 0; off >>= 1) {
                if (t < off) {
                    const float ov = s_val[t + off]; const int oi = s_idx[t + off];
                    if (ov > s_val[t] || (ov == s_val[t] && oi < s_idx[t])) {
                        s_val[t] = ov; s_idx[t] = oi;
                    }
                }
                __syncthreads();
            }
            if (t == 0) { s_win[k] = s_idx[0]; s_wk[s_idx[0]] = -INFINITY; }
            __syncthreads();
        }

        // rowsums over the 3 winners (unweighted f)
        float part = 0.0f;
        for (int k = 0; k < 3; ++k) {
            const int row = s_win[k];
            const float pk = s_p[row], rk = s_r[row];
            for (int c = 0; c < 4; ++c) {
                const int j = t + c * BTH;
                part += pair_f(pk, rk, s_p[j], s_r[j]);
            }
        }
        for (int off = 32; off > 0; off >>= 1) part += __shfl_down(part, off);
        if ((t & 63) == 0) s_red[t >> 6] = part;
        __syncthreads();
        if (t == 0) {
            const float R = s_red[0] + s_red[1] + s_red[2] + s_red[3];
            const int a = s_win[0], c2 = s_win[1], d = s_win[2];
            const float TT = 2.0f * (pair_f(s_p[a],  s_r[a],  s_p[c2], s_r[c2])
                                   + pair_f(s_p[a],  s_r[a],  s_p[d],  s_r[d])
                                   + pair_f(s_p[c2], s_r[c2], s_p[d],  s_r[d]));
            corr[b] = 2.0f * R + TT;
            int s2 = 0;
            for (int g = 0; g < 5; ++g) s2 += s_hist[g] * s_hist[g];
            cntv[b] = (float)(NN * NN - s2);
        }
    }
}

// ---------------------------------------------------------------------------
// Finalize: loss = mean_b( (S_b + corr_b) / (cnt_b + 1e-8) )
// ---------------------------------------------------------------------------
__global__ void finalize_kernel(const float* __restrict__ psum,
                                const float* __restrict__ corr,
                                const float* __restrict__ cntv,
                                float* __restrict__ out, int B) {
    const int t = threadIdx.x;
    __shared__ float s_l[32];
    const int b = t >> 3, k = t & 7;
    float s = 0.0f;
    if (b < B) {
        for (int e = k; e < NTILES; e += 8) s += psum[(size_t)b * NTILES + e];
    }
    s += __shfl_xor(s, 1);
    s += __shfl_xor(s, 2);
    s += __shfl_xor(s, 4);
    if (b < B && k == 0) s_l[b] = (s + corr[b]) / (cntv[b] + 1e-8f);
    __syncthreads();
    if (t == 0) {
        float m = 0.0f;
        for (int i = 0; i < B; ++i) m += s_l[i];
        out[0] = m / (float)B;
    }
}

extern "C" void kernel_launch(void* const* d_in, const int* in_sizes, int n_in,
                              void* d_out, int out_size, void* d_ws, size_t ws_size,
                              hipStream_t stream) {
    const float* pred = (const float*)d_in[0];
    const float* rel  = (const float*)d_in[1];
    float* out = (float*)d_out;

    const int B = in_sizes[0] / NN;  // 32

    // ws (floats): psum[B*NTILES] | corr[B] | cntv[B]
    float* psum = (float*)d_ws;
    float* corr = psum + (size_t)B * NTILES;
    float* cntv = corr + B;

    main_kernel<<<TBLK * B + B, BTH, 0, stream>>>(pred, rel, psum, corr, cntv, B);
    finalize_kernel<<<1, BTH, 0, stream>>>(psum, corr, cntv, out, B);
}